// Round 6
// baseline (431.895 us; speedup 1.0000x reference)
//
#include <hip/hip_runtime.h>

// Problem constants (fixed by setup_inputs)
#define N_  2
#define C_  12
#define D_  8
#define HG  16
#define WG  16
#define H_  2048
#define W_  2048
#define HW_ (H_*W_)

// Native clang vector (HIP's float4 is a class -> rejected by
// __builtin_nontemporal_load/store; ext_vector_type is accepted).
typedef float f4 __attribute__((ext_vector_type(4)));

// Prepass: transpose grid [N,C,D,Hg,Wg] -> T [N,D,Hg,Wg,C]
// so the 12 channels of one (z,y,x) cell are contiguous (48 B, 16B-aligned).
__global__ __launch_bounds__(256) void transpose_grid_k(const float* __restrict__ g,
                                                        float* __restrict__ T) {
    int i = blockIdx.x * 256 + threadIdx.x;
    if (i >= N_ * C_ * D_ * HG * WG) return;
    int x = i & (WG - 1); int t = i >> 4;
    int y = t & (HG - 1); t >>= 4;
    int z = t & (D_ - 1); t >>= 3;
    int c = t % C_;
    int n = t / C_;
    T[(((n * D_ + z) * HG + y) * WG + x) * C_ + c] = g[i];
}

// One block = one full image row (2048 px). h uniform within block.
// A/B vs R4: output stores are PLAIN (cached) instead of nontemporal.
// Everything else identical. Theory: the nt flag on global stores demotes
// the L2 write-combining path (fill kernel: 6.3 TB/s plain stores; us:
// 2.6 TB/s NT stores) and is the residual ~100us.
__global__ __launch_bounds__(256, 4) void slice_k(const float* __restrict__ T,
                                                  const float* __restrict__ guide,
                                                  float* __restrict__ out) {
    __shared__ float Lg[HG * D_ * C_];   // 6 KiB, [y][z][c]

    const int tid = threadIdx.x;
    const int b   = blockIdx.x;          // [0, N_*H_)
    const int h   = b & (H_ - 1);
    const int n   = b >> 11;

    const int rowg = n * HW_ + h * W_;            // guide row base
    const int rowo = n * (C_ * HW_) + h * W_;     // out row base (channel 0)

    // ---- guide prefetch: issue both segments' loads up front ----
    const f4 g0 = __builtin_nontemporal_load((const f4*)(guide + rowg + tid * 4));
    const f4 g1 = __builtin_nontemporal_load((const f4*)(guide + rowg + 1024 + tid * 4));

    // ---- x interpolation factors (uniform across block) ----
    float xg   = (float)h / (H_ - 1) * 2.0f - 1.0f;
    float ixf  = (xg + 1.0f) * 0.5f * (WG - 1);   // in [0,15] exactly
    float ix0f = floorf(ixf);
    float fx   = ixf - ix0f;
    int   x0   = (int)ix0f;
    int   x1   = min(x0 + 1, WG - 1);             // x0=15 only when fx==0
    float wx0  = 1.0f - fx;
    float wx1  = fx;

    // ---- stage x-interpolated grid into LDS, layout [y][z][c] ----
    const float* Tn = T + n * (D_ * HG * WG * C_);
    for (int i = tid; i < D_ * HG * C_; i += 256) {
        int c  = i % C_;
        int yz = i / C_;                 // y*8 + z  (LDS-layout index)
        int z  = yz & (D_ - 1);
        int y  = yz >> 3;
        const float* s = Tn + (z * HG + y) * (WG * C_) + c;
        Lg[i] = wx0 * s[x0 * C_] + wx1 * s[x1 * C_];
    }
    __syncthreads();

    auto process = [&](f4 g4, int wbase) {
        const float ga[4] = { g4.x, g4.y, g4.z, g4.w };

        // per-pixel weights + LDS offsets (static-indexed arrays -> regs)
        float w00a[4], w01a[4], w10a[4], w11a[4];
        int   o00a[4], o01a[4], o10a[4], o11a[4];

#pragma unroll
        for (int p = 0; p < 4; ++p) {
            const int w = wbase + p;

            // y interpolation: iyf = w * 15/2047, provably in [0,15]
            float iyf  = (float)w * ((float)(HG - 1) / (float)(W_ - 1));
            float iy0f = floorf(iyf);
            float fy   = iyf - iy0f;
            int   y0   = (int)iy0f;
            int   y1   = min(y0 + 1, HG - 1);     // y0=15 only when fy==0
            float wy0  = 1.0f - fy;
            float wy1  = fy;

            // z interpolation (data-dependent; keep full validity masks)
            float izf  = fmaf(ga[p], 0.5f * (D_ - 1), 0.5f * (D_ - 1));
            float iz0f = floorf(izf);
            float fz   = izf - iz0f;
            int   z0   = (int)iz0f, z1 = z0 + 1;
            float wz0  = (1.0f - fz) * ((z0 >= 0 && z0 < D_) ? 1.0f : 0.0f);
            float wz1  = fz          * ((z1 >= 0 && z1 < D_) ? 1.0f : 0.0f);
            z0 = min(max(z0, 0), D_ - 1);
            z1 = min(max(z1, 0), D_ - 1);

            // [y][z][c] layout: offset = (y*D_ + z)*C_
            o00a[p] = (y0 * D_ + z0) * C_;        // wz0*wy0
            o01a[p] = (y1 * D_ + z0) * C_;        // wz0*wy1
            o10a[p] = (y0 * D_ + z1) * C_;        // wz1*wy0
            o11a[p] = (y1 * D_ + z1) * C_;        // wz1*wy1
            w00a[p] = wz0 * wy0;
            w01a[p] = wz0 * wy1;
            w10a[p] = wz1 * wy0;
            w11a[p] = wz1 * wy1;
        }

        float* outp = out + rowo + wbase;

#pragma unroll
        for (int j = 0; j < 3; ++j) {
            f4 t[4];                              // [pixel], static idx
#pragma unroll
            for (int p = 0; p < 4; ++p) {
                f4 c00 = *(const f4*)(Lg + o00a[p] + j * 4);
                f4 c01 = *(const f4*)(Lg + o01a[p] + j * 4);
                f4 c10 = *(const f4*)(Lg + o10a[p] + j * 4);
                f4 c11 = *(const f4*)(Lg + o11a[p] + j * 4);
                f4 v;
                v.x = fmaf(w00a[p], c00.x, fmaf(w01a[p], c01.x, fmaf(w10a[p], c10.x, w11a[p] * c11.x)));
                v.y = fmaf(w00a[p], c00.y, fmaf(w01a[p], c01.y, fmaf(w10a[p], c10.y, w11a[p] * c11.y)));
                v.z = fmaf(w00a[p], c00.z, fmaf(w01a[p], c01.z, fmaf(w10a[p], c10.z, w11a[p] * c11.z)));
                v.w = fmaf(w00a[p], c00.w, fmaf(w01a[p], c01.w, fmaf(w10a[p], c10.w, w11a[p] * c11.w)));
                t[p] = v;
            }
            // transpose 4x4 in regs: channel k across the lane's 4 pixels
            // PLAIN stores (the A/B variable): let L2 write-combine.
#pragma unroll
            for (int k = 0; k < 4; ++k) {
                f4 o = { t[0][k], t[1][k], t[2][k], t[3][k] };
                *(f4*)(outp + (j * 4 + k) * HW_) = o;
            }
        }
    };

    process(g0, tid * 4);
    process(g1, 1024 + tid * 4);
}

extern "C" void kernel_launch(void* const* d_in, const int* in_sizes, int n_in,
                              void* d_out, int out_size, void* d_ws, size_t ws_size,
                              hipStream_t stream) {
    const float* grid  = (const float*)d_in[0];  // [2,12,8,16,16]
    const float* guide = (const float*)d_in[1];  // [2,1,2048,2048]
    float* out = (float*)d_out;                  // [2,12,2048,2048]
    float* T   = (float*)d_ws;                   // 49152 floats = 192 KiB scratch

    hipLaunchKernelGGL(transpose_grid_k, dim3(192), dim3(256), 0, stream, grid, T);
    // one block per image row
    hipLaunchKernelGGL(slice_k, dim3(N_ * H_), dim3(256), 0, stream,
                       T, guide, out);
}